// Round 5
// baseline (234.269 us; speedup 1.0000x reference)
//
#include <hip/hip_runtime.h>

typedef unsigned short u16;
typedef unsigned int u32;

#define HNUM 16
#define NSEQ 4096
#define CDIM 1024
#define SCALE 0.125f
#define LOG2E 1.4426950408889634f

using bf16x8 = __attribute__((ext_vector_type(8))) __bf16;
using f32x4  = __attribute__((ext_vector_type(4))) float;
using u32x4  = __attribute__((ext_vector_type(4))) u32;

__device__ __forceinline__ u16 f2bf(float f) {
  union { float f; u32 u; } v; v.f = f;
  u32 u = v.u;
  return (u16)((u + 0x7fffu + ((u >> 16) & 1u)) >> 16);
}
__device__ __forceinline__ float fexp2(float x) { return __builtin_amdgcn_exp2f(x); }

__device__ __forceinline__ f32x4 mfma16(bf16x8 a, bf16x8 b, f32x4 c) {
  return __builtin_amdgcn_mfma_f32_16x16x32_bf16(a, b, c, 0, 0, 0);
}

// pack 2 f32 -> 1 dword of 2 bf16 (round-half-up): lo16=bf(a), hi16=bf(b)
__device__ __forceinline__ u32 pack2(float a, float b) {
  union { float f; u32 u; } A, B;
  A.f = a; B.f = b;
  return __builtin_amdgcn_perm(B.u + 0x8000u, A.u + 0x8000u, 0x07060302u);
}

// async global->LDS, 16B/lane; LDS dest = wave-uniform base + lane*16
__device__ __forceinline__ void g2l16(const void* g, void* l) {
  __builtin_amdgcn_global_load_lds(
      (const __attribute__((address_space(1))) unsigned int*)(unsigned long long)g,
      (__attribute__((address_space(3))) unsigned int*)(unsigned int)(unsigned long long)l,
      16, 0, 0);
}

// ---- merged prep kernel: x1 cvt + 3 convert-transposes, range-dispatched ----
__device__ __forceinline__ void cvtT_body(const float* __restrict__ in,
                                          u16* __restrict__ out, int R, int C,
                                          int bx, int by, float scale, int tid) {
  __shared__ u16 t[64][65];
  const int r0 = by * 64, c0 = bx * 64;
  const int tr = tid >> 2, tc = (tid & 3) * 16;
  const float* src = in + (r0 + tr) * C + c0 + tc;
#pragma unroll
  for (int i = 0; i < 16; ++i) t[tr][tc + i] = f2bf(src[i] * scale);
  __syncthreads();
  u16* dst = out + (c0 + tr) * R + r0 + tc;
#pragma unroll
  for (int i = 0; i < 16; ++i) dst[i] = t[tc + i][tr];
}

// blocks: [0,2048) x1 cvt | [2048,2560) Wqkv T | [2560,2816) Wproj T | [2816,3840) x2 T
__global__ __launch_bounds__(256) void prep_k(const float* __restrict__ x1,
                                              u16* __restrict__ x1b,
                                              const float* __restrict__ Wqkv,
                                              u16* __restrict__ WqT,
                                              const float* __restrict__ Wproj,
                                              u16* __restrict__ WpT,
                                              const float* __restrict__ x2,
                                              u16* __restrict__ Vt,
                                              float cfac) {
  const int b = blockIdx.x, tid = threadIdx.x;
  if (b < 2048) {
    const int i = (b * 256 + tid) * 8;
    const float4 f0 = *(const float4*)(x1 + i);
    const float4 f1 = *(const float4*)(x1 + i + 4);
    u32 d[4] = {pack2(f0.x, f0.y), pack2(f0.z, f0.w),
                pack2(f1.x, f1.y), pack2(f1.z, f1.w)};
    *(bf16x8*)(x1b + i) = *(bf16x8*)d;
  } else if (b < 2560) {
    const int rel = b - 2048;                     // Wqkv: R=1024 C=2048, 32x16
    const int bx = rel & 31, by = rel >> 5;
    cvtT_body(Wqkv, WqT, 1024, 2048, bx, by, bx < 16 ? cfac : 1.0f, tid);
  } else if (b < 2816) {
    const int rel = b - 2560;                     // Wproj: R=C=1024, 16x16
    const int bx = rel & 15, by = rel >> 4;
    cvtT_body(Wproj, WpT, 1024, 1024, bx, by, 1.0f, tid);
  } else {
    const int rel = b - 2816;                     // x2: R=4096 C=1024, 16x64
    const int bx = rel & 15, by = rel >> 4;
    cvtT_body(x2, Vt, 4096, 1024, bx, by, 1.0f, tid);
  }
}

// QK = x1b(bf16 MxK) @ WqT(bf16 NxK)^T -> bf16. 128M x 64N tiles, single-buffer,
// 1024 blocks = 4/CU = 16 waves/CU (occupancy-based latency hiding).
__global__ __launch_bounds__(256) void gemm1_k(const u16* __restrict__ A,
                                               const u16* __restrict__ Bt,
                                               u16* __restrict__ C,
                                               int M, int N, int K) {
  __shared__ __align__(16) u16 As[128 * 64];
  __shared__ __align__(16) u16 Bs[64 * 64];
  const int tid = threadIdx.x;
  const int wave = tid >> 6, lane = tid & 63;
  const int quad = lane >> 4, l16 = lane & 15;
  const int m0 = blockIdx.y * 128, n0 = blockIdx.x * 64;
  const int wm = wave * 32;
  const int lrow = lane >> 3, lc8 = (lane & 7) * 8;

  f32x4 acc[2][4] = {};
  for (int k0 = 0; k0 < K; k0 += 64) {
#pragma unroll
    for (int c = 0; c < 4; ++c) {
      const int cw = wave * 4 + c;
      g2l16(A + (m0 + cw * 8 + lrow) * K + k0 + lc8, (char*)As + cw * 1024);
    }
#pragma unroll
    for (int c = 0; c < 2; ++c) {
      const int cw = wave * 2 + c;
      g2l16(Bt + (n0 + cw * 8 + lrow) * K + k0 + lc8, (char*)Bs + cw * 1024);
    }
    __syncthreads();
#pragma unroll
    for (int ks = 0; ks < 2; ++ks) {
      bf16x8 a[2], b[4];
#pragma unroll
      for (int mt = 0; mt < 2; ++mt)
        a[mt] = *(const bf16x8*)(As + (wm + mt * 16 + l16) * 64 + ks * 32 + quad * 8);
#pragma unroll
      for (int nt = 0; nt < 4; ++nt)
        b[nt] = *(const bf16x8*)(Bs + (nt * 16 + l16) * 64 + ks * 32 + quad * 8);
#pragma unroll
      for (int mt = 0; mt < 2; ++mt)
#pragma unroll
        for (int nt = 0; nt < 4; ++nt)
          acc[mt][nt] = mfma16(a[mt], b[nt], acc[mt][nt]);
    }
    __syncthreads();
  }
#pragma unroll
  for (int mt = 0; mt < 2; ++mt)
#pragma unroll
    for (int nt = 0; nt < 4; ++nt)
#pragma unroll
      for (int r = 0; r < 4; ++r)
        C[(m0 + wm + mt * 16 + quad * 4 + r) * N + n0 + nt * 16 + l16] =
            f2bf(acc[mt][nt][r]);
}

// out = Obf(bf16 MxK) @ WpT(bf16 NxK)^T + bias(f32) -> f32. 128x64, dbuf.
__global__ __launch_bounds__(256) void gemm2_k(const u16* __restrict__ A,
                                               const u16* __restrict__ Bt,
                                               float* __restrict__ C,
                                               const float* __restrict__ bias,
                                               int M, int N, int K) {
  __shared__ __align__(16) u16 As[2][128 * 64];
  __shared__ __align__(16) u16 Bs[2][64 * 64];
  const int tid = threadIdx.x;
  const int wave = tid >> 6, lane = tid & 63;
  const int quad = lane >> 4, l16 = lane & 15;
  const int m0 = blockIdx.y * 128, n0 = blockIdx.x * 64;
  const int wm = wave * 32;
  const int lrow = lane >> 3, lc8 = (lane & 7) * 8;

  f32x4 acc[2][4] = {};
#pragma unroll
  for (int c = 0; c < 4; ++c) {
    const int cw = wave * 4 + c;
    g2l16(A + (m0 + cw * 8 + lrow) * K + lc8, (char*)As[0] + cw * 1024);
  }
#pragma unroll
  for (int c = 0; c < 2; ++c) {
    const int cw = wave * 2 + c;
    g2l16(Bt + (n0 + cw * 8 + lrow) * K + lc8, (char*)Bs[0] + cw * 1024);
  }
  const int NIT = K / 64;
  for (int it = 0; it < NIT; ++it) {
    const int cur = it & 1;
    __syncthreads();
    if (it + 1 < NIT) {
      const int k0 = (it + 1) * 64;
#pragma unroll
      for (int c = 0; c < 4; ++c) {
        const int cw = wave * 4 + c;
        g2l16(A + (m0 + cw * 8 + lrow) * K + k0 + lc8, (char*)As[1 - cur] + cw * 1024);
      }
#pragma unroll
      for (int c = 0; c < 2; ++c) {
        const int cw = wave * 2 + c;
        g2l16(Bt + (n0 + cw * 8 + lrow) * K + k0 + lc8, (char*)Bs[1 - cur] + cw * 1024);
      }
    }
#pragma unroll
    for (int ks = 0; ks < 2; ++ks) {
      bf16x8 a[2], b[4];
#pragma unroll
      for (int mt = 0; mt < 2; ++mt)
        a[mt] = *(const bf16x8*)(As[cur] + (wm + mt * 16 + l16) * 64 + ks * 32 + quad * 8);
#pragma unroll
      for (int nt = 0; nt < 4; ++nt)
        b[nt] = *(const bf16x8*)(Bs[cur] + (nt * 16 + l16) * 64 + ks * 32 + quad * 8);
#pragma unroll
      for (int mt = 0; mt < 2; ++mt)
#pragma unroll
        for (int nt = 0; nt < 4; ++nt)
          acc[mt][nt] = mfma16(a[mt], b[nt], acc[mt][nt]);
    }
  }
#pragma unroll
  for (int mt = 0; mt < 2; ++mt)
#pragma unroll
    for (int nt = 0; nt < 4; ++nt)
#pragma unroll
      for (int r = 0; r < 4; ++r) {
        const int col = n0 + nt * 16 + l16;
        C[(m0 + wm + mt * 16 + quad * 4 + r) * N + col] = acc[mt][nt][r] + bias[col];
      }
}

// Flash attention v6c: EXACT revert to R2-verified v6b (4 waves/block,
// 32 q-rows/wave, shared K/V staging, MFMA ones-B row-sums, pack2 everywhere)
// + single delta: s_setprio(1/0) around the two MFMA clusters (T5).
// NOTE: the 8-wave/16-row restructure (R3/R4) produced nondeterministic
// output (tripwire divergence) — convicted by correlation, do not reintroduce
// without a root-cause. cvt_pk paths exonerated by R4 (failed with pack2).
__global__ __launch_bounds__(256) void attn_k(const u16* __restrict__ QK,
                                              const u16* __restrict__ Vt,
                                              u16* __restrict__ O) {
  __shared__ __align__(16) u16 Ks[2][64 * 64];  // [key][d], swizzled
  __shared__ __align__(16) u16 Vs[2][64 * 64];  // [d][key], swizzled
  __shared__ __align__(16) u16 Ps[4][32 * 64];  // per-wave [q][key] bf16, swizzled
  const int tid = threadIdx.x;
  const int wave = tid >> 6, lane = tid & 63;
  const int quad = lane >> 4, l16 = lane & 15;
  const int head = blockIdx.y;
  const int qb = blockIdx.x * 128 + wave * 32;
  const int lrow = lane >> 3;               // staging row within 8-row chunk
  const int lc8 = ((lane & 7) ^ lrow) * 8;  // staging logical col (u16 units)
  const int swz = (quad ^ (l16 & 7)) * 8;   // frag-read swizzle base (ks=0)

  // 8 chunks of 1KB each for Ks and Vs, 2 chunks per wave (shared staging)
  const u16* kp[2];
  const u16* vp[2];
#pragma unroll
  for (int c = 0; c < 2; ++c) {
    const int row = (wave * 2 + c) * 8 + lrow;
    kp[c] = QK + row * 2048 + CDIM + head * 64 + lc8;  // +64*2048 per iter
    vp[c] = Vt + (head * 64 + row) * NSEQ + lc8;       // +64 per iter
  }

  bf16x8 qf[2][2];
#pragma unroll
  for (int mt = 0; mt < 2; ++mt)
#pragma unroll
    for (int ks = 0; ks < 2; ++ks)
      qf[mt][ks] = *(const bf16x8*)(QK + (qb + mt * 16 + l16) * 2048 + head * 64 +
                                    ks * 32 + quad * 8);

  // ones B-fragment for row-sum MFMA (register-built, alignment-safe)
  union { u32x4 u; bf16x8 b; } OU;
  OU.u = (u32x4){0x3F803F80u, 0x3F803F80u, 0x3F803F80u, 0x3F803F80u};
  const bf16x8 onesf = OU.b;

  f32x4 o[2][4] = {};
  f32x4 ol[2] = {};  // row-sums: ol[mt][r] = sum over keys for row quad*4+r
  u16* Pw = Ps[wave];

#pragma unroll
  for (int c = 0; c < 2; ++c) {
    const int cw = wave * 2 + c;
    g2l16(kp[c], (char*)Ks[0] + cw * 1024);
    g2l16(vp[c], (char*)Vs[0] + cw * 1024);
    kp[c] += 64 * 2048;
    vp[c] += 64;
  }

  for (int kt = 0; kt < NSEQ / 64; ++kt) {
    const int cur = kt & 1;
    __syncthreads();  // publishes buf[cur] (drains vmcnt)

    if (kt < NSEQ / 64 - 1) {
#pragma unroll
      for (int c = 0; c < 2; ++c) {
        const int cw = wave * 2 + c;
        g2l16(kp[c], (char*)Ks[1 - cur] + cw * 1024);
        g2l16(vp[c], (char*)Vs[1 - cur] + cw * 1024);
        kp[c] += 64 * 2048;
        vp[c] += 64;
      }
    }

    const u16* Kc = Ks[cur];
    const u16* Vc = Vs[cur];

    f32x4 s[2][4] = {};
    __builtin_amdgcn_s_setprio(1);
#pragma unroll
    for (int ks = 0; ks < 2; ++ks)
#pragma unroll
      for (int nt = 0; nt < 4; ++nt) {
        const bf16x8 kf =
            *(const bf16x8*)(Kc + (nt * 16 + l16) * 64 + (swz ^ (ks * 32)));
#pragma unroll
        for (int mt = 0; mt < 2; ++mt)
          s[mt][nt] = mfma16(kf, qf[mt][ks], s[mt][nt]);
      }
    __builtin_amdgcn_s_setprio(0);

#pragma unroll
    for (int mt = 0; mt < 2; ++mt)
#pragma unroll
      for (int nt = 0; nt < 4; ++nt) {
        const float p0 = fexp2(s[mt][nt][0]);
        const float p1 = fexp2(s[mt][nt][1]);
        const float p2 = fexp2(s[mt][nt][2]);
        const float p3 = fexp2(s[mt][nt][3]);
        u32 d01 = pack2(p0, p1), d23 = pack2(p2, p3);
        const int col8 = (nt * 2 + (quad >> 1)) ^ (l16 & 7);
        u32* dst = (u32*)(Pw + (mt * 16 + l16) * 64 + col8 * 8 + (quad & 1) * 4);
        dst[0] = d01; dst[1] = d23;  // ds_write_b64
      }

    __builtin_amdgcn_s_setprio(1);
#pragma unroll
    for (int ks = 0; ks < 2; ++ks) {
      bf16x8 pf[2];
#pragma unroll
      for (int mt = 0; mt < 2; ++mt)
        pf[mt] = *(const bf16x8*)(Pw + (mt * 16 + l16) * 64 + (swz ^ (ks * 32)));
#pragma unroll
      for (int dt = 0; dt < 4; ++dt) {
        const bf16x8 vf =
            *(const bf16x8*)(Vc + (dt * 16 + l16) * 64 + (swz ^ (ks * 32)));
#pragma unroll
        for (int mt = 0; mt < 2; ++mt)
          o[mt][dt] = mfma16(pf[mt], vf, o[mt][dt]);
      }
#pragma unroll
      for (int mt = 0; mt < 2; ++mt)
        ol[mt] = mfma16(pf[mt], onesf, ol[mt]);  // row-sum accumulate
    }
    __builtin_amdgcn_s_setprio(0);
  }

  // o and ol share the same A-fragment (pf), hence the same C/D row mapping:
  // ol[mt][r] is the row-sum for the exact row o[mt][*][r] holds. No shuffles.
#pragma unroll
  for (int mt = 0; mt < 2; ++mt)
#pragma unroll
    for (int r = 0; r < 4; ++r) {
      const float lv = 1.0f / ol[mt][r];
#pragma unroll
      for (int dt = 0; dt < 4; ++dt)
        O[(qb + mt * 16 + quad * 4 + r) * CDIM + head * 64 + dt * 16 + l16] =
            f2bf(o[mt][dt][r] * lv);
    }
}

extern "C" void kernel_launch(void* const* d_in, const int* in_sizes, int n_in,
                              void* d_out, int out_size, void* d_ws, size_t ws_size,
                              hipStream_t stream) {
  const float* x1    = (const float*)d_in[0];  // 4096x1024 f32
  const float* x2    = (const float*)d_in[1];  // 4096x1024 f32
  const float* Wqkv  = (const float*)d_in[2];  // 1024x2048 f32
  const float* Wproj = (const float*)d_in[3];  // 1024x1024 f32
  const float* bproj = (const float*)d_in[4];  // 1024 f32
  float* out = (float*)d_out;                  // 4096x1024 f32

  char* ws = (char*)d_ws;
  u16* QK  = (u16*)(ws);                      // 4096x2048 bf16 (16MB)
  u16* Vt  = (u16*)(ws + 16u * 1024 * 1024);  // 1024x4096 bf16 (8MB)
  u16* Obf = (u16*)(ws + 24u * 1024 * 1024);  // 4096x1024 bf16 (8MB)
  u16* WpT = (u16*)(ws + 32u * 1024 * 1024);  // 1024x1024 bf16 (2MB)
  u16* WqT = (u16*)(ws + 34u * 1024 * 1024);  // 2048x1024 bf16 (4MB)
  u16* x1b = (u16*)(ws + 38u * 1024 * 1024);  // 4096x1024 bf16 (8MB)

  const float cfac = SCALE * LOG2E;  // softmax scale folded into q-cols of Wqkv

  prep_k<<<dim3(3840), 256, 0, stream>>>(x1, x1b, Wqkv, WqT, Wproj, WpT, x2, Vt,
                                         cfac);
  gemm1_k<<<dim3(2048 / 64, 4096 / 128), 256, 0, stream>>>(x1b, WqT, QK,
                                                           4096, 2048, 1024);
  attn_k<<<dim3(4096 / 128, HNUM), 256, 0, stream>>>(QK, Vt, Obf);
  gemm2_k<<<dim3(1024 / 64, 4096 / 128), 256, 0, stream>>>(Obf, WpT, out, bproj,
                                                           4096, 1024, 1024);
}

// Round 6
// 233.556 us; speedup vs baseline: 1.0031x; 1.0031x over previous
//
#include <hip/hip_runtime.h>

typedef unsigned short u16;
typedef unsigned int u32;

#define HNUM 16
#define NSEQ 4096
#define CDIM 1024
#define SCALE 0.125f
#define LOG2E 1.4426950408889634f

using bf16x8 = __attribute__((ext_vector_type(8))) __bf16;
using f32x4  = __attribute__((ext_vector_type(4))) float;
using u32x4  = __attribute__((ext_vector_type(4))) u32;

__device__ __forceinline__ u16 f2bf(float f) {
  union { float f; u32 u; } v; v.f = f;
  u32 u = v.u;
  return (u16)((u + 0x7fffu + ((u >> 16) & 1u)) >> 16);
}
__device__ __forceinline__ float fexp2(float x) { return __builtin_amdgcn_exp2f(x); }

__device__ __forceinline__ f32x4 mfma16(bf16x8 a, bf16x8 b, f32x4 c) {
  return __builtin_amdgcn_mfma_f32_16x16x32_bf16(a, b, c, 0, 0, 0);
}

// pack 2 f32 -> 1 dword of 2 bf16 (round-half-up): lo16=bf(a), hi16=bf(b)
__device__ __forceinline__ u32 pack2(float a, float b) {
  union { float f; u32 u; } A, B;
  A.f = a; B.f = b;
  return __builtin_amdgcn_perm(B.u + 0x8000u, A.u + 0x8000u, 0x07060302u);
}

// async global->LDS, 16B/lane; LDS dest = wave-uniform base + lane*16
__device__ __forceinline__ void g2l16(const void* g, void* l) {
  __builtin_amdgcn_global_load_lds(
      (const __attribute__((address_space(1))) unsigned int*)(unsigned long long)g,
      (__attribute__((address_space(3))) unsigned int*)(unsigned int)(unsigned long long)l,
      16, 0, 0);
}

// ---- merged prep kernel: x1 cvt + 3 convert-transposes, range-dispatched ----
__device__ __forceinline__ void cvtT_body(const float* __restrict__ in,
                                          u16* __restrict__ out, int R, int C,
                                          int bx, int by, float scale, int tid) {
  __shared__ u16 t[64][65];
  const int r0 = by * 64, c0 = bx * 64;
  const int tr = tid >> 2, tc = (tid & 3) * 16;
  const float* src = in + (r0 + tr) * C + c0 + tc;
#pragma unroll
  for (int i = 0; i < 16; ++i) t[tr][tc + i] = f2bf(src[i] * scale);
  __syncthreads();
  u16* dst = out + (c0 + tr) * R + r0 + tc;
#pragma unroll
  for (int i = 0; i < 16; ++i) dst[i] = t[tc + i][tr];
}

// blocks: [0,2048) x1 cvt | [2048,2560) Wqkv T | [2560,2816) Wproj T | [2816,3840) x2 T
__global__ __launch_bounds__(256) void prep_k(const float* __restrict__ x1,
                                              u16* __restrict__ x1b,
                                              const float* __restrict__ Wqkv,
                                              u16* __restrict__ WqT,
                                              const float* __restrict__ Wproj,
                                              u16* __restrict__ WpT,
                                              const float* __restrict__ x2,
                                              u16* __restrict__ Vt,
                                              float cfac) {
  const int b = blockIdx.x, tid = threadIdx.x;
  if (b < 2048) {
    const int i = (b * 256 + tid) * 8;
    const float4 f0 = *(const float4*)(x1 + i);
    const float4 f1 = *(const float4*)(x1 + i + 4);
    u32 d[4] = {pack2(f0.x, f0.y), pack2(f0.z, f0.w),
                pack2(f1.x, f1.y), pack2(f1.z, f1.w)};
    *(bf16x8*)(x1b + i) = *(bf16x8*)d;
  } else if (b < 2560) {
    const int rel = b - 2048;                     // Wqkv: R=1024 C=2048, 32x16
    const int bx = rel & 31, by = rel >> 5;
    cvtT_body(Wqkv, WqT, 1024, 2048, bx, by, bx < 16 ? cfac : 1.0f, tid);
  } else if (b < 2816) {
    const int rel = b - 2560;                     // Wproj: R=C=1024, 16x16
    const int bx = rel & 15, by = rel >> 4;
    cvtT_body(Wproj, WpT, 1024, 1024, bx, by, 1.0f, tid);
  } else {
    const int rel = b - 2816;                     // x2: R=4096 C=1024, 16x64
    const int bx = rel & 15, by = rel >> 4;
    cvtT_body(x2, Vt, 4096, 1024, bx, by, 1.0f, tid);
  }
}

// QK = x1b(bf16 MxK) @ WqT(bf16 NxK)^T -> bf16. 128M x 64N tiles, single-buffer,
// 1024 blocks = 4/CU = 16 waves/CU (occupancy-based latency hiding).
__global__ __launch_bounds__(256) void gemm1_k(const u16* __restrict__ A,
                                               const u16* __restrict__ Bt,
                                               u16* __restrict__ C,
                                               int M, int N, int K) {
  __shared__ __align__(16) u16 As[128 * 64];
  __shared__ __align__(16) u16 Bs[64 * 64];
  const int tid = threadIdx.x;
  const int wave = tid >> 6, lane = tid & 63;
  const int quad = lane >> 4, l16 = lane & 15;
  const int m0 = blockIdx.y * 128, n0 = blockIdx.x * 64;
  const int wm = wave * 32;
  const int lrow = lane >> 3, lc8 = (lane & 7) * 8;

  f32x4 acc[2][4] = {};
  for (int k0 = 0; k0 < K; k0 += 64) {
#pragma unroll
    for (int c = 0; c < 4; ++c) {
      const int cw = wave * 4 + c;
      g2l16(A + (m0 + cw * 8 + lrow) * K + k0 + lc8, (char*)As + cw * 1024);
    }
#pragma unroll
    for (int c = 0; c < 2; ++c) {
      const int cw = wave * 2 + c;
      g2l16(Bt + (n0 + cw * 8 + lrow) * K + k0 + lc8, (char*)Bs + cw * 1024);
    }
    __syncthreads();
#pragma unroll
    for (int ks = 0; ks < 2; ++ks) {
      bf16x8 a[2], b[4];
#pragma unroll
      for (int mt = 0; mt < 2; ++mt)
        a[mt] = *(const bf16x8*)(As + (wm + mt * 16 + l16) * 64 + ks * 32 + quad * 8);
#pragma unroll
      for (int nt = 0; nt < 4; ++nt)
        b[nt] = *(const bf16x8*)(Bs + (nt * 16 + l16) * 64 + ks * 32 + quad * 8);
#pragma unroll
      for (int mt = 0; mt < 2; ++mt)
#pragma unroll
        for (int nt = 0; nt < 4; ++nt)
          acc[mt][nt] = mfma16(a[mt], b[nt], acc[mt][nt]);
    }
    __syncthreads();
  }
#pragma unroll
  for (int mt = 0; mt < 2; ++mt)
#pragma unroll
    for (int nt = 0; nt < 4; ++nt)
#pragma unroll
      for (int r = 0; r < 4; ++r)
        C[(m0 + wm + mt * 16 + quad * 4 + r) * N + n0 + nt * 16 + l16] =
            f2bf(acc[mt][nt][r]);
}

// out = Obf(bf16 MxK) @ WpT(bf16 NxK)^T + bias(f32) -> f32. 128x64, dbuf.
__global__ __launch_bounds__(256) void gemm2_k(const u16* __restrict__ A,
                                               const u16* __restrict__ Bt,
                                               float* __restrict__ C,
                                               const float* __restrict__ bias,
                                               int M, int N, int K) {
  __shared__ __align__(16) u16 As[2][128 * 64];
  __shared__ __align__(16) u16 Bs[2][64 * 64];
  const int tid = threadIdx.x;
  const int wave = tid >> 6, lane = tid & 63;
  const int quad = lane >> 4, l16 = lane & 15;
  const int m0 = blockIdx.y * 128, n0 = blockIdx.x * 64;
  const int wm = wave * 32;
  const int lrow = lane >> 3, lc8 = (lane & 7) * 8;

  f32x4 acc[2][4] = {};
#pragma unroll
  for (int c = 0; c < 4; ++c) {
    const int cw = wave * 4 + c;
    g2l16(A + (m0 + cw * 8 + lrow) * K + lc8, (char*)As[0] + cw * 1024);
  }
#pragma unroll
  for (int c = 0; c < 2; ++c) {
    const int cw = wave * 2 + c;
    g2l16(Bt + (n0 + cw * 8 + lrow) * K + lc8, (char*)Bs[0] + cw * 1024);
  }
  const int NIT = K / 64;
  for (int it = 0; it < NIT; ++it) {
    const int cur = it & 1;
    __syncthreads();
    if (it + 1 < NIT) {
      const int k0 = (it + 1) * 64;
#pragma unroll
      for (int c = 0; c < 4; ++c) {
        const int cw = wave * 4 + c;
        g2l16(A + (m0 + cw * 8 + lrow) * K + k0 + lc8, (char*)As[1 - cur] + cw * 1024);
      }
#pragma unroll
      for (int c = 0; c < 2; ++c) {
        const int cw = wave * 2 + c;
        g2l16(Bt + (n0 + cw * 8 + lrow) * K + k0 + lc8, (char*)Bs[1 - cur] + cw * 1024);
      }
    }
#pragma unroll
    for (int ks = 0; ks < 2; ++ks) {
      bf16x8 a[2], b[4];
#pragma unroll
      for (int mt = 0; mt < 2; ++mt)
        a[mt] = *(const bf16x8*)(As[cur] + (wm + mt * 16 + l16) * 64 + ks * 32 + quad * 8);
#pragma unroll
      for (int nt = 0; nt < 4; ++nt)
        b[nt] = *(const bf16x8*)(Bs[cur] + (nt * 16 + l16) * 64 + ks * 32 + quad * 8);
#pragma unroll
      for (int mt = 0; mt < 2; ++mt)
#pragma unroll
        for (int nt = 0; nt < 4; ++nt)
          acc[mt][nt] = mfma16(a[mt], b[nt], acc[mt][nt]);
    }
  }
#pragma unroll
  for (int mt = 0; mt < 2; ++mt)
#pragma unroll
    for (int nt = 0; nt < 4; ++nt)
#pragma unroll
      for (int r = 0; r < 4; ++r) {
        const int col = n0 + nt * 16 + l16;
        C[(m0 + wm + mt * 16 + quad * 4 + r) * N + col] = acc[mt][nt][r] + bias[col];
      }
}

// Flash attention v8: R2-verified v6b structure (4 waves/block, 32 q-rows/wave,
// shared K/V staging, MFMA ones-B row-sums, pack2) with ONE delta:
// two 64-key subtiles per barrier (double-buffered PAIRS of tiles, LDS 80KB,
// still 2 blocks/CU). Barriers halve 64->32 -> more inter-wave phase drift
// (MFMA/VALU overlap) and half the barrier-drain events.
// setprio REMOVED (R5: +7us regression — lockstep structure, T5 inapplicable).
// 8-wave remap convicted nondeterministic (R3/R4); do not reintroduce.
__global__ __launch_bounds__(256) void attn_k(const u16* __restrict__ QK,
                                              const u16* __restrict__ Vt,
                                              u16* __restrict__ O) {
  __shared__ __align__(16) u16 Ks[2][2][64 * 64];  // [dbuf][subtile][key][d]
  __shared__ __align__(16) u16 Vs[2][2][64 * 64];  // [dbuf][subtile][d][key]
  __shared__ __align__(16) u16 Ps[4][32 * 64];     // per-wave [q][key] bf16
  const int tid = threadIdx.x;
  const int wave = tid >> 6, lane = tid & 63;
  const int quad = lane >> 4, l16 = lane & 15;
  const int head = blockIdx.y;
  const int qb = blockIdx.x * 128 + wave * 32;
  const int lrow = lane >> 3;               // staging row within 8-row chunk
  const int lc8 = ((lane & 7) ^ lrow) * 8;  // staging logical col (u16 units)
  const int swz = (quad ^ (l16 & 7)) * 8;   // frag-read swizzle base (ks=0)

  // 8 chunks of 1KB per 64-key tile for Ks and Vs, 2 chunks per wave
  const u16* kp[2];
  const u16* vp[2];
#pragma unroll
  for (int c = 0; c < 2; ++c) {
    const int row = (wave * 2 + c) * 8 + lrow;
    kp[c] = QK + row * 2048 + CDIM + head * 64 + lc8;  // +64*2048 per tile
    vp[c] = Vt + (head * 64 + row) * NSEQ + lc8;       // +64 per tile
  }

  bf16x8 qf[2][2];
#pragma unroll
  for (int mt = 0; mt < 2; ++mt)
#pragma unroll
    for (int ks = 0; ks < 2; ++ks)
      qf[mt][ks] = *(const bf16x8*)(QK + (qb + mt * 16 + l16) * 2048 + head * 64 +
                                    ks * 32 + quad * 8);

  // ones B-fragment for row-sum MFMA (register-built, alignment-safe)
  union { u32x4 u; bf16x8 b; } OU;
  OU.u = (u32x4){0x3F803F80u, 0x3F803F80u, 0x3F803F80u, 0x3F803F80u};
  const bf16x8 onesf = OU.b;

  f32x4 o[2][4] = {};
  f32x4 ol[2] = {};  // row-sums: ol[mt][r] = sum over keys for row quad*4+r
  u16* Pw = Ps[wave];

  // prologue: stage tile pair 0 (subtiles 0,1) into dbuf 0
#pragma unroll
  for (int s = 0; s < 2; ++s)
#pragma unroll
    for (int c = 0; c < 2; ++c) {
      const int cw = wave * 2 + c;
      g2l16(kp[c], (char*)Ks[0][s] + cw * 1024);
      g2l16(vp[c], (char*)Vs[0][s] + cw * 1024);
      kp[c] += 64 * 2048;
      vp[c] += 64;
    }

  const int NIT = NSEQ / 128;  // 32 pair-iterations
  for (int it = 0; it < NIT; ++it) {
    const int cur = it & 1;
    __syncthreads();  // publishes dbuf[cur] pair (drains vmcnt)

    if (it + 1 < NIT) {
#pragma unroll
      for (int s = 0; s < 2; ++s)
#pragma unroll
        for (int c = 0; c < 2; ++c) {
          const int cw = wave * 2 + c;
          g2l16(kp[c], (char*)Ks[1 - cur][s] + cw * 1024);
          g2l16(vp[c], (char*)Vs[1 - cur][s] + cw * 1024);
          kp[c] += 64 * 2048;
          vp[c] += 64;
        }
    }

#pragma unroll
    for (int s = 0; s < 2; ++s) {
      const u16* Kc = Ks[cur][s];
      const u16* Vc = Vs[cur][s];

      f32x4 sacc[2][4] = {};
#pragma unroll
      for (int ks = 0; ks < 2; ++ks)
#pragma unroll
        for (int nt = 0; nt < 4; ++nt) {
          const bf16x8 kf =
              *(const bf16x8*)(Kc + (nt * 16 + l16) * 64 + (swz ^ (ks * 32)));
#pragma unroll
          for (int mt = 0; mt < 2; ++mt)
            sacc[mt][nt] = mfma16(kf, qf[mt][ks], sacc[mt][nt]);
        }

#pragma unroll
      for (int mt = 0; mt < 2; ++mt)
#pragma unroll
        for (int nt = 0; nt < 4; ++nt) {
          const float p0 = fexp2(sacc[mt][nt][0]);
          const float p1 = fexp2(sacc[mt][nt][1]);
          const float p2 = fexp2(sacc[mt][nt][2]);
          const float p3 = fexp2(sacc[mt][nt][3]);
          u32 d01 = pack2(p0, p1), d23 = pack2(p2, p3);
          const int col8 = (nt * 2 + (quad >> 1)) ^ (l16 & 7);
          u32* dst = (u32*)(Pw + (mt * 16 + l16) * 64 + col8 * 8 + (quad & 1) * 4);
          dst[0] = d01; dst[1] = d23;  // ds_write_b64
        }

#pragma unroll
      for (int ks = 0; ks < 2; ++ks) {
        bf16x8 pf[2];
#pragma unroll
        for (int mt = 0; mt < 2; ++mt)
          pf[mt] = *(const bf16x8*)(Pw + (mt * 16 + l16) * 64 + (swz ^ (ks * 32)));
#pragma unroll
        for (int dt = 0; dt < 4; ++dt) {
          const bf16x8 vf =
              *(const bf16x8*)(Vc + (dt * 16 + l16) * 64 + (swz ^ (ks * 32)));
#pragma unroll
          for (int mt = 0; mt < 2; ++mt)
            o[mt][dt] = mfma16(pf[mt], vf, o[mt][dt]);
        }
#pragma unroll
        for (int mt = 0; mt < 2; ++mt)
          ol[mt] = mfma16(pf[mt], onesf, ol[mt]);  // row-sum accumulate
      }
    }
  }

  // o and ol share the same A-fragment (pf), hence the same C/D row mapping:
  // ol[mt][r] is the row-sum for the exact row o[mt][*][r] holds. No shuffles.
#pragma unroll
  for (int mt = 0; mt < 2; ++mt)
#pragma unroll
    for (int r = 0; r < 4; ++r) {
      const float lv = 1.0f / ol[mt][r];
#pragma unroll
      for (int dt = 0; dt < 4; ++dt)
        O[(qb + mt * 16 + quad * 4 + r) * CDIM + head * 64 + dt * 16 + l16] =
            f2bf(o[mt][dt][r] * lv);
    }
}

extern "C" void kernel_launch(void* const* d_in, const int* in_sizes, int n_in,
                              void* d_out, int out_size, void* d_ws, size_t ws_size,
                              hipStream_t stream) {
  const float* x1    = (const float*)d_in[0];  // 4096x1024 f32
  const float* x2    = (const float*)d_in[1];  // 4096x1024 f32
  const float* Wqkv  = (const float*)d_in[2];  // 1024x2048 f32
  const float* Wproj = (const float*)d_in[3];  // 1024x1024 f32
  const float* bproj = (const float*)d_in[4];  // 1024 f32
  float* out = (float*)d_out;                  // 4096x1024 f32

  char* ws = (char*)d_ws;
  u16* QK  = (u16*)(ws);                      // 4096x2048 bf16 (16MB)
  u16* Vt  = (u16*)(ws + 16u * 1024 * 1024);  // 1024x4096 bf16 (8MB)
  u16* Obf = (u16*)(ws + 24u * 1024 * 1024);  // 4096x1024 bf16 (8MB)
  u16* WpT = (u16*)(ws + 32u * 1024 * 1024);  // 1024x1024 bf16 (2MB)
  u16* WqT = (u16*)(ws + 34u * 1024 * 1024);  // 2048x1024 bf16 (4MB)
  u16* x1b = (u16*)(ws + 38u * 1024 * 1024);  // 4096x1024 bf16 (8MB)

  const float cfac = SCALE * LOG2E;  // softmax scale folded into q-cols of Wqkv

  prep_k<<<dim3(3840), 256, 0, stream>>>(x1, x1b, Wqkv, WqT, Wproj, WpT, x2, Vt,
                                         cfac);
  gemm1_k<<<dim3(2048 / 64, 4096 / 128), 256, 0, stream>>>(x1b, WqT, QK,
                                                           4096, 2048, 1024);
  attn_k<<<dim3(4096 / 128, HNUM), 256, 0, stream>>>(QK, Vt, Obf);
  gemm2_k<<<dim3(1024 / 64, 4096 / 128), 256, 0, stream>>>(Obf, WpT, out, bproj,
                                                           4096, 1024, 1024);
}

// Round 7
// 228.180 us; speedup vs baseline: 1.0267x; 1.0236x over previous
//
#include <hip/hip_runtime.h>

typedef unsigned short u16;
typedef unsigned int u32;

#define HNUM 16
#define NSEQ 4096
#define CDIM 1024
#define SCALE 0.125f
#define LOG2E 1.4426950408889634f

using bf16x8 = __attribute__((ext_vector_type(8))) __bf16;
using f32x4  = __attribute__((ext_vector_type(4))) float;
using u32x4  = __attribute__((ext_vector_type(4))) u32;

__device__ __forceinline__ u16 f2bf(float f) {
  union { float f; u32 u; } v; v.f = f;
  u32 u = v.u;
  return (u16)((u + 0x7fffu + ((u >> 16) & 1u)) >> 16);
}
__device__ __forceinline__ float fexp2(float x) { return __builtin_amdgcn_exp2f(x); }

__device__ __forceinline__ f32x4 mfma16(bf16x8 a, bf16x8 b, f32x4 c) {
  return __builtin_amdgcn_mfma_f32_16x16x32_bf16(a, b, c, 0, 0, 0);
}

// pack 2 f32 -> 1 dword of 2 bf16 (round-half-up): lo16=bf(a), hi16=bf(b)
__device__ __forceinline__ u32 pack2(float a, float b) {
  union { float f; u32 u; } A, B;
  A.f = a; B.f = b;
  return __builtin_amdgcn_perm(B.u + 0x8000u, A.u + 0x8000u, 0x07060302u);
}

// async global->LDS, 16B/lane; LDS dest = wave-uniform base + lane*16
__device__ __forceinline__ void g2l16(const void* g, void* l) {
  __builtin_amdgcn_global_load_lds(
      (const __attribute__((address_space(1))) unsigned int*)(unsigned long long)g,
      (__attribute__((address_space(3))) unsigned int*)(unsigned int)(unsigned long long)l,
      16, 0, 0);
}

// ---- merged prep kernel: x1 cvt + 3 convert-transposes, range-dispatched ----
__device__ __forceinline__ void cvtT_body(const float* __restrict__ in,
                                          u16* __restrict__ out, int R, int C,
                                          int bx, int by, float scale, int tid) {
  __shared__ u16 t[64][65];
  const int r0 = by * 64, c0 = bx * 64;
  const int tr = tid >> 2, tc = (tid & 3) * 16;
  const float* src = in + (r0 + tr) * C + c0 + tc;
#pragma unroll
  for (int i = 0; i < 16; ++i) t[tr][tc + i] = f2bf(src[i] * scale);
  __syncthreads();
  u16* dst = out + (c0 + tr) * R + r0 + tc;
#pragma unroll
  for (int i = 0; i < 16; ++i) dst[i] = t[tc + i][tr];
}

// blocks: [0,2048) x1 cvt | [2048,2560) Wqkv T | [2560,2816) Wproj T | [2816,3840) x2 T
__global__ __launch_bounds__(256) void prep_k(const float* __restrict__ x1,
                                              u16* __restrict__ x1b,
                                              const float* __restrict__ Wqkv,
                                              u16* __restrict__ WqT,
                                              const float* __restrict__ Wproj,
                                              u16* __restrict__ WpT,
                                              const float* __restrict__ x2,
                                              u16* __restrict__ Vt,
                                              float cfac) {
  const int b = blockIdx.x, tid = threadIdx.x;
  if (b < 2048) {
    const int i = (b * 256 + tid) * 8;
    const float4 f0 = *(const float4*)(x1 + i);
    const float4 f1 = *(const float4*)(x1 + i + 4);
    u32 d[4] = {pack2(f0.x, f0.y), pack2(f0.z, f0.w),
                pack2(f1.x, f1.y), pack2(f1.z, f1.w)};
    *(bf16x8*)(x1b + i) = *(bf16x8*)d;
  } else if (b < 2560) {
    const int rel = b - 2048;                     // Wqkv: R=1024 C=2048, 32x16
    const int bx = rel & 31, by = rel >> 5;
    cvtT_body(Wqkv, WqT, 1024, 2048, bx, by, bx < 16 ? cfac : 1.0f, tid);
  } else if (b < 2816) {
    const int rel = b - 2560;                     // Wproj: R=C=1024, 16x16
    const int bx = rel & 15, by = rel >> 4;
    cvtT_body(Wproj, WpT, 1024, 1024, bx, by, 1.0f, tid);
  } else {
    const int rel = b - 2816;                     // x2: R=4096 C=1024, 16x64
    const int bx = rel & 15, by = rel >> 4;
    cvtT_body(x2, Vt, 4096, 1024, bx, by, 1.0f, tid);
  }
}

// QK = x1b(bf16 MxK) @ WqT(bf16 NxK)^T -> bf16. NEW (R7): 128x128 tile +
// double-buffer (m93/m97 verified shape; dbuf skeleton cloned from gemm2_k).
// Grid 512 = 2 blocks/CU (64KB LDS also allows exactly 2). acc 2x8 per wave.
__global__ __launch_bounds__(256) void gemm1_k(const u16* __restrict__ A,
                                               const u16* __restrict__ Bt,
                                               u16* __restrict__ C,
                                               int M, int N, int K) {
  __shared__ __align__(16) u16 As[2][128 * 64];
  __shared__ __align__(16) u16 Bs[2][128 * 64];
  const int tid = threadIdx.x;
  const int wave = tid >> 6, lane = tid & 63;
  const int quad = lane >> 4, l16 = lane & 15;
  const int m0 = blockIdx.y * 128, n0 = blockIdx.x * 128;
  const int wm = wave * 32;
  const int lrow = lane >> 3, lc8 = (lane & 7) * 8;

  f32x4 acc[2][8] = {};
#pragma unroll
  for (int c = 0; c < 4; ++c) {
    const int cw = wave * 4 + c;
    g2l16(A + (m0 + cw * 8 + lrow) * K + lc8, (char*)As[0] + cw * 1024);
    g2l16(Bt + (n0 + cw * 8 + lrow) * K + lc8, (char*)Bs[0] + cw * 1024);
  }
  const int NIT = K / 64;
  for (int it = 0; it < NIT; ++it) {
    const int cur = it & 1;
    __syncthreads();
    if (it + 1 < NIT) {
      const int k0 = (it + 1) * 64;
#pragma unroll
      for (int c = 0; c < 4; ++c) {
        const int cw = wave * 4 + c;
        g2l16(A + (m0 + cw * 8 + lrow) * K + k0 + lc8, (char*)As[1 - cur] + cw * 1024);
        g2l16(Bt + (n0 + cw * 8 + lrow) * K + k0 + lc8, (char*)Bs[1 - cur] + cw * 1024);
      }
    }
#pragma unroll
    for (int ks = 0; ks < 2; ++ks) {
      bf16x8 a[2], b[8];
#pragma unroll
      for (int mt = 0; mt < 2; ++mt)
        a[mt] = *(const bf16x8*)(As[cur] + (wm + mt * 16 + l16) * 64 + ks * 32 + quad * 8);
#pragma unroll
      for (int nt = 0; nt < 8; ++nt)
        b[nt] = *(const bf16x8*)(Bs[cur] + (nt * 16 + l16) * 64 + ks * 32 + quad * 8);
#pragma unroll
      for (int mt = 0; mt < 2; ++mt)
#pragma unroll
        for (int nt = 0; nt < 8; ++nt)
          acc[mt][nt] = mfma16(a[mt], b[nt], acc[mt][nt]);
    }
  }
#pragma unroll
  for (int mt = 0; mt < 2; ++mt)
#pragma unroll
    for (int nt = 0; nt < 8; ++nt)
#pragma unroll
      for (int r = 0; r < 4; ++r)
        C[(m0 + wm + mt * 16 + quad * 4 + r) * N + n0 + nt * 16 + l16] =
            f2bf(acc[mt][nt][r]);
}

// out = Obf(bf16 MxK) @ WpT(bf16 NxK)^T + bias(f32) -> f32. 128x64, dbuf.
__global__ __launch_bounds__(256) void gemm2_k(const u16* __restrict__ A,
                                               const u16* __restrict__ Bt,
                                               float* __restrict__ C,
                                               const float* __restrict__ bias,
                                               int M, int N, int K) {
  __shared__ __align__(16) u16 As[2][128 * 64];
  __shared__ __align__(16) u16 Bs[2][64 * 64];
  const int tid = threadIdx.x;
  const int wave = tid >> 6, lane = tid & 63;
  const int quad = lane >> 4, l16 = lane & 15;
  const int m0 = blockIdx.y * 128, n0 = blockIdx.x * 64;
  const int wm = wave * 32;
  const int lrow = lane >> 3, lc8 = (lane & 7) * 8;

  f32x4 acc[2][4] = {};
#pragma unroll
  for (int c = 0; c < 4; ++c) {
    const int cw = wave * 4 + c;
    g2l16(A + (m0 + cw * 8 + lrow) * K + lc8, (char*)As[0] + cw * 1024);
  }
#pragma unroll
  for (int c = 0; c < 2; ++c) {
    const int cw = wave * 2 + c;
    g2l16(Bt + (n0 + cw * 8 + lrow) * K + lc8, (char*)Bs[0] + cw * 1024);
  }
  const int NIT = K / 64;
  for (int it = 0; it < NIT; ++it) {
    const int cur = it & 1;
    __syncthreads();
    if (it + 1 < NIT) {
      const int k0 = (it + 1) * 64;
#pragma unroll
      for (int c = 0; c < 4; ++c) {
        const int cw = wave * 4 + c;
        g2l16(A + (m0 + cw * 8 + lrow) * K + k0 + lc8, (char*)As[1 - cur] + cw * 1024);
      }
#pragma unroll
      for (int c = 0; c < 2; ++c) {
        const int cw = wave * 2 + c;
        g2l16(Bt + (n0 + cw * 8 + lrow) * K + k0 + lc8, (char*)Bs[1 - cur] + cw * 1024);
      }
    }
#pragma unroll
    for (int ks = 0; ks < 2; ++ks) {
      bf16x8 a[2], b[4];
#pragma unroll
      for (int mt = 0; mt < 2; ++mt)
        a[mt] = *(const bf16x8*)(As[cur] + (wm + mt * 16 + l16) * 64 + ks * 32 + quad * 8);
#pragma unroll
      for (int nt = 0; nt < 4; ++nt)
        b[nt] = *(const bf16x8*)(Bs[cur] + (nt * 16 + l16) * 64 + ks * 32 + quad * 8);
#pragma unroll
      for (int mt = 0; mt < 2; ++mt)
#pragma unroll
        for (int nt = 0; nt < 4; ++nt)
          acc[mt][nt] = mfma16(a[mt], b[nt], acc[mt][nt]);
    }
  }
#pragma unroll
  for (int mt = 0; mt < 2; ++mt)
#pragma unroll
    for (int nt = 0; nt < 4; ++nt)
#pragma unroll
      for (int r = 0; r < 4; ++r) {
        const int col = n0 + nt * 16 + l16;
        C[(m0 + wm + mt * 16 + quad * 4 + r) * N + col] = acc[mt][nt][r] + bias[col];
      }
}

// Flash attention v6b (R2-verified, byte-exact revert): 4 waves/block,
// 32 q-rows/wave, shared K/V staging, MFMA ones-B row-sums, pack2.
// CONVICTED (do not reintroduce without root-cause):
//  - 8-wave/16-row remap (R3/R4): nondeterministic output (tripwire).
//  - s_setprio around MFMA (R5): +7us (lockstep structure, T5 inapplicable).
//  - two-subtile-per-barrier pairing (R6): +6us (extra VALU/addressing,
//    longer vmcnt drains; barrier count was not the stall).
__global__ __launch_bounds__(256) void attn_k(const u16* __restrict__ QK,
                                              const u16* __restrict__ Vt,
                                              u16* __restrict__ O) {
  __shared__ __align__(16) u16 Ks[2][64 * 64];  // [key][d], swizzled
  __shared__ __align__(16) u16 Vs[2][64 * 64];  // [d][key], swizzled
  __shared__ __align__(16) u16 Ps[4][32 * 64];  // per-wave [q][key] bf16, swizzled
  const int tid = threadIdx.x;
  const int wave = tid >> 6, lane = tid & 63;
  const int quad = lane >> 4, l16 = lane & 15;
  const int head = blockIdx.y;
  const int qb = blockIdx.x * 128 + wave * 32;
  const int lrow = lane >> 3;               // staging row within 8-row chunk
  const int lc8 = ((lane & 7) ^ lrow) * 8;  // staging logical col (u16 units)
  const int swz = (quad ^ (l16 & 7)) * 8;   // frag-read swizzle base (ks=0)

  // 8 chunks of 1KB each for Ks and Vs, 2 chunks per wave (shared staging)
  const u16* kp[2];
  const u16* vp[2];
#pragma unroll
  for (int c = 0; c < 2; ++c) {
    const int row = (wave * 2 + c) * 8 + lrow;
    kp[c] = QK + row * 2048 + CDIM + head * 64 + lc8;  // +64*2048 per iter
    vp[c] = Vt + (head * 64 + row) * NSEQ + lc8;       // +64 per iter
  }

  bf16x8 qf[2][2];
#pragma unroll
  for (int mt = 0; mt < 2; ++mt)
#pragma unroll
    for (int ks = 0; ks < 2; ++ks)
      qf[mt][ks] = *(const bf16x8*)(QK + (qb + mt * 16 + l16) * 2048 + head * 64 +
                                    ks * 32 + quad * 8);

  // ones B-fragment for row-sum MFMA (register-built, alignment-safe)
  union { u32x4 u; bf16x8 b; } OU;
  OU.u = (u32x4){0x3F803F80u, 0x3F803F80u, 0x3F803F80u, 0x3F803F80u};
  const bf16x8 onesf = OU.b;

  f32x4 o[2][4] = {};
  f32x4 ol[2] = {};  // row-sums: ol[mt][r] = sum over keys for row quad*4+r
  u16* Pw = Ps[wave];

#pragma unroll
  for (int c = 0; c < 2; ++c) {
    const int cw = wave * 2 + c;
    g2l16(kp[c], (char*)Ks[0] + cw * 1024);
    g2l16(vp[c], (char*)Vs[0] + cw * 1024);
    kp[c] += 64 * 2048;
    vp[c] += 64;
  }

  for (int kt = 0; kt < NSEQ / 64; ++kt) {
    const int cur = kt & 1;
    __syncthreads();  // publishes buf[cur] (drains vmcnt)

    if (kt < NSEQ / 64 - 1) {
#pragma unroll
      for (int c = 0; c < 2; ++c) {
        const int cw = wave * 2 + c;
        g2l16(kp[c], (char*)Ks[1 - cur] + cw * 1024);
        g2l16(vp[c], (char*)Vs[1 - cur] + cw * 1024);
        kp[c] += 64 * 2048;
        vp[c] += 64;
      }
    }

    const u16* Kc = Ks[cur];
    const u16* Vc = Vs[cur];

    f32x4 s[2][4] = {};
#pragma unroll
    for (int ks = 0; ks < 2; ++ks)
#pragma unroll
      for (int nt = 0; nt < 4; ++nt) {
        const bf16x8 kf =
            *(const bf16x8*)(Kc + (nt * 16 + l16) * 64 + (swz ^ (ks * 32)));
#pragma unroll
        for (int mt = 0; mt < 2; ++mt)
          s[mt][nt] = mfma16(kf, qf[mt][ks], s[mt][nt]);
      }

#pragma unroll
    for (int mt = 0; mt < 2; ++mt)
#pragma unroll
      for (int nt = 0; nt < 4; ++nt) {
        const float p0 = fexp2(s[mt][nt][0]);
        const float p1 = fexp2(s[mt][nt][1]);
        const float p2 = fexp2(s[mt][nt][2]);
        const float p3 = fexp2(s[mt][nt][3]);
        u32 d01 = pack2(p0, p1), d23 = pack2(p2, p3);
        const int col8 = (nt * 2 + (quad >> 1)) ^ (l16 & 7);
        u32* dst = (u32*)(Pw + (mt * 16 + l16) * 64 + col8 * 8 + (quad & 1) * 4);
        dst[0] = d01; dst[1] = d23;  // ds_write_b64
      }

#pragma unroll
    for (int ks = 0; ks < 2; ++ks) {
      bf16x8 pf[2];
#pragma unroll
      for (int mt = 0; mt < 2; ++mt)
        pf[mt] = *(const bf16x8*)(Pw + (mt * 16 + l16) * 64 + (swz ^ (ks * 32)));
#pragma unroll
      for (int dt = 0; dt < 4; ++dt) {
        const bf16x8 vf =
            *(const bf16x8*)(Vc + (dt * 16 + l16) * 64 + (swz ^ (ks * 32)));
#pragma unroll
        for (int mt = 0; mt < 2; ++mt)
          o[mt][dt] = mfma16(pf[mt], vf, o[mt][dt]);
      }
#pragma unroll
      for (int mt = 0; mt < 2; ++mt)
        ol[mt] = mfma16(pf[mt], onesf, ol[mt]);  // row-sum accumulate
    }
  }

  // o and ol share the same A-fragment (pf), hence the same C/D row mapping:
  // ol[mt][r] is the row-sum for the exact row o[mt][*][r] holds. No shuffles.
#pragma unroll
  for (int mt = 0; mt < 2; ++mt)
#pragma unroll
    for (int r = 0; r < 4; ++r) {
      const float lv = 1.0f / ol[mt][r];
#pragma unroll
      for (int dt = 0; dt < 4; ++dt)
        O[(qb + mt * 16 + quad * 4 + r) * CDIM + head * 64 + dt * 16 + l16] =
            f2bf(o[mt][dt][r] * lv);
    }
}

extern "C" void kernel_launch(void* const* d_in, const int* in_sizes, int n_in,
                              void* d_out, int out_size, void* d_ws, size_t ws_size,
                              hipStream_t stream) {
  const float* x1    = (const float*)d_in[0];  // 4096x1024 f32
  const float* x2    = (const float*)d_in[1];  // 4096x1024 f32
  const float* Wqkv  = (const float*)d_in[2];  // 1024x2048 f32
  const float* Wproj = (const float*)d_in[3];  // 1024x1024 f32
  const float* bproj = (const float*)d_in[4];  // 1024 f32
  float* out = (float*)d_out;                  // 4096x1024 f32

  char* ws = (char*)d_ws;
  u16* QK  = (u16*)(ws);                      // 4096x2048 bf16 (16MB)
  u16* Vt  = (u16*)(ws + 16u * 1024 * 1024);  // 1024x4096 bf16 (8MB)
  u16* Obf = (u16*)(ws + 24u * 1024 * 1024);  // 4096x1024 bf16 (8MB)
  u16* WpT = (u16*)(ws + 32u * 1024 * 1024);  // 1024x1024 bf16 (2MB)
  u16* WqT = (u16*)(ws + 34u * 1024 * 1024);  // 2048x1024 bf16 (4MB)
  u16* x1b = (u16*)(ws + 38u * 1024 * 1024);  // 4096x1024 bf16 (8MB)

  const float cfac = SCALE * LOG2E;  // softmax scale folded into q-cols of Wqkv

  prep_k<<<dim3(3840), 256, 0, stream>>>(x1, x1b, Wqkv, WqT, Wproj, WpT, x2, Vt,
                                         cfac);
  gemm1_k<<<dim3(2048 / 128, 4096 / 128), 256, 0, stream>>>(x1b, WqT, QK,
                                                            4096, 2048, 1024);
  attn_k<<<dim3(4096 / 128, HNUM), 256, 0, stream>>>(QK, Vt, Obf);
  gemm2_k<<<dim3(1024 / 64, 4096 / 128), 256, 0, stream>>>(Obf, WpT, out, bproj,
                                                           4096, 1024, 1024);
}